// Round 2
// baseline (725.949 us; speedup 1.0000x reference)
//
#include <hip/hip_runtime.h>

// ---------------------------------------------------------------------------
// xp = x @ W_ih^T + (b_ih + b_hh)        [bf16 MFMA GEMM, BM=64, 2 blk/CU]
// h_t = tanh(xp_t + W_hh @ h^T)          [MFMA scan: W_hh in regs as A-frags,
//                                         h in LDS bf16, 1 barrier/step]
// out = LN(relu(relu(hT W1^T+b1) W2^T+b2))   [fused tail]
// ---------------------------------------------------------------------------

typedef __bf16 bf16x8 __attribute__((ext_vector_type(8)));
typedef float  f32x4  __attribute__((ext_vector_type(4)));

#define T_STEPS 512
#define I_DIM   2048
#define H_DIM   128
#define B_DIM   64
#define M_TOT   (B_DIM * T_STEPS)

__device__ __forceinline__ unsigned short f2bf(float f) {
    unsigned int u = __float_as_uint(f);
    u += 0x7FFFu + ((u >> 16) & 1u);
    return (unsigned short)(u >> 16);
}
__device__ __forceinline__ float bf2f(unsigned short u) {
    return __uint_as_float(((unsigned int)u) << 16);
}
__device__ __forceinline__ bf16x8 packbf8(float4 lo, float4 hi) {
    union { bf16x8 v; unsigned short u[8]; } r;
    r.u[0] = f2bf(lo.x); r.u[1] = f2bf(lo.y); r.u[2] = f2bf(lo.z); r.u[3] = f2bf(lo.w);
    r.u[4] = f2bf(hi.x); r.u[5] = f2bf(hi.y); r.u[6] = f2bf(hi.z); r.u[7] = f2bf(hi.w);
    return r.v;
}
// tanh(a) = (e^{2a}-1)/(e^{2a}+1); |a| <= ~24 here so e^{2a} is finite.
__device__ __forceinline__ float tanh_fast(float a) {
    float q = __expf(a + a);
    return (q - 1.f) * __builtin_amdgcn_rcpf(q + 1.f);
}

// ---------------------------------------------------------------------------
// Kernel 1: xp[M,128] = x[M,2048]bf16 @ W_ih[128,2048]^T bf16 + bias
// ---------------------------------------------------------------------------
#define BM  64
#define BK  64
#define LDK 72

__global__ __launch_bounds__(256) void gemm_xp(
    const float* __restrict__ x, const float* __restrict__ w,
    const float* __restrict__ b_ih, const float* __restrict__ b_hh,
    float* __restrict__ xp)
{
    __shared__ __align__(16) unsigned short As[BM * LDK];     // 9.0 KB
    __shared__ __align__(16) unsigned short Bs[H_DIM * LDK];  // 18.4 KB

    const int tid = threadIdx.x;
    const int m0  = blockIdx.x * BM;
    const int r0  = tid >> 4;
    const int c4  = tid & 15;
    const int lane = tid & 63, wave = tid >> 6;
    const int wm = (wave >> 1) * 32;
    const int wn = (wave & 1) * 64;
    const int l16 = lane & 15, quad = lane >> 4;

    f32x4 acc[2][4] = {};
    float4 ar[4], br[8];

    auto load_tiles = [&](int k0) {
        #pragma unroll
        for (int i = 0; i < 4; ++i)
            ar[i] = *(const float4*)(x + (size_t)(m0 + i * 16 + r0) * I_DIM + k0 + c4 * 4);
        #pragma unroll
        for (int i = 0; i < 8; ++i)
            br[i] = *(const float4*)(w + (size_t)(i * 16 + r0) * I_DIM + k0 + c4 * 4);
    };
    auto store_tiles = [&]() {
        #pragma unroll
        for (int i = 0; i < 4; ++i) {
            ushort4 v; v.x = f2bf(ar[i].x); v.y = f2bf(ar[i].y);
                       v.z = f2bf(ar[i].z); v.w = f2bf(ar[i].w);
            *(ushort4*)(As + (i * 16 + r0) * LDK + c4 * 4) = v;
        }
        #pragma unroll
        for (int i = 0; i < 8; ++i) {
            ushort4 v; v.x = f2bf(br[i].x); v.y = f2bf(br[i].y);
                       v.z = f2bf(br[i].z); v.w = f2bf(br[i].w);
            *(ushort4*)(Bs + (i * 16 + r0) * LDK + c4 * 4) = v;
        }
    };

    load_tiles(0);
    for (int k0 = 0; k0 < I_DIM; k0 += BK) {
        __syncthreads();
        store_tiles();
        if (k0 + BK < I_DIM) load_tiles(k0 + BK);
        __syncthreads();
        #pragma unroll
        for (int kt = 0; kt < 2; ++kt) {
            bf16x8 af[2], bfr[4];
            #pragma unroll
            for (int i = 0; i < 2; ++i)
                af[i] = *(const bf16x8*)(As + (wm + i * 16 + l16) * LDK + kt * 32 + quad * 8);
            #pragma unroll
            for (int j = 0; j < 4; ++j)
                bfr[j] = *(const bf16x8*)(Bs + (wn + j * 16 + l16) * LDK + kt * 32 + quad * 8);
            #pragma unroll
            for (int i = 0; i < 2; ++i)
                #pragma unroll
                for (int j = 0; j < 4; ++j)
                    acc[i][j] = __builtin_amdgcn_mfma_f32_16x16x32_bf16(af[i], bfr[j], acc[i][j], 0, 0, 0);
        }
    }
    #pragma unroll
    for (int j = 0; j < 4; ++j) {
        const int col = wn + j * 16 + l16;
        const float bias = b_ih[col] + b_hh[col];
        #pragma unroll
        for (int i = 0; i < 2; ++i)
            #pragma unroll
            for (int r = 0; r < 4; ++r) {
                const int row = wm + i * 16 + quad * 4 + r;
                xp[(size_t)(m0 + row) * H_DIM + col] = acc[i][j][r] + bias;
            }
    }
}

// ---------------------------------------------------------------------------
// Kernel 2: MFMA scan. 4 blocks x 256 thr (4 waves). Block: 16 batches.
// Per step: D[feat 128, batch 16] = W_hh(A-frags, regs) x h^T(B-frags, LDS).
// Wave w owns features [32w, 32w+32) (2 M-tiles). One barrier/step.
// h stored bf16 [16][LDH=136] (272B rows: b128 reads at 8-pass floor).
// ---------------------------------------------------------------------------
#define NB  16
#define LDH 136

__global__ __launch_bounds__(256) void rnn_scan(
    const float* __restrict__ xp,   // [64,512,128], bias pre-added
    const float* __restrict__ Whh,  // [128,128]
    const float* __restrict__ W1, const float* __restrict__ b1,
    const float* __restrict__ W2, const float* __restrict__ b2,
    const float* __restrict__ gamma, const float* __restrict__ beta,
    float* __restrict__ out)        // [64,128]
{
    __shared__ __align__(16) unsigned short hbuf[2][NB * LDH];  // 8.7 KB
    __shared__ float ztmp[NB][129];   // FC1 out (fp32)
    __shared__ float ztmp2[NB][129];  // FC2 out (fp32)

    const int tid  = threadIdx.x;
    const int lane = tid & 63, w = tid >> 6;     // wave 0..3
    const int l16  = lane & 15, quad = lane >> 4;
    const int b0   = blockIdx.x * NB;

    // --- W_hh -> static A-frags: afr[tile][kstep], feature row = 32w+16t+l16,
    //     elements k = 32*ks + 8*quad + [0..8)
    bf16x8 afr[2][4];
    #pragma unroll
    for (int t = 0; t < 2; ++t) {
        const float* wrow = Whh + (32 * w + 16 * t + l16) * H_DIM;
        #pragma unroll
        for (int ks = 0; ks < 4; ++ks) {
            float4 lo = *(const float4*)(wrow + 32 * ks + 8 * quad);
            float4 hi = *(const float4*)(wrow + 32 * ks + 8 * quad + 4);
            afr[t][ks] = packbf8(lo, hi);
        }
    }

    // xp in C-layout: batch = l16, features 32w + 16t + 4*quad + [0..4)
    const float* xpb = xp + (size_t)(b0 + l16) * T_STEPS * H_DIM + 32 * w + 4 * quad;
    float4 xc0 = *(const float4*)(xpb);
    float4 xc1 = *(const float4*)(xpb + 16);

    for (int i = tid; i < NB * LDH; i += 256) hbuf[0][i] = 0;  // h0 = 0
    __syncthreads();

    const f32x4 z4 = {0.f, 0.f, 0.f, 0.f};
    const int rbase = l16 * LDH + quad * 8;

    for (int t = 0; t < T_STEPS; ++t) {
        const unsigned short* hb = hbuf[t & 1];
        bf16x8 bf0 = *(const bf16x8*)(hb + rbase);
        bf16x8 bf1 = *(const bf16x8*)(hb + rbase + 32);
        bf16x8 bf2 = *(const bf16x8*)(hb + rbase + 64);
        bf16x8 bf3 = *(const bf16x8*)(hb + rbase + 96);

        // prefetch next step's xp while MFMA/tanh run
        const int tn = (t + 1 < T_STEPS) ? t + 1 : t;
        float4 xn0 = *(const float4*)(xpb + (size_t)tn * H_DIM);
        float4 xn1 = *(const float4*)(xpb + (size_t)tn * H_DIM + 16);

        unsigned short* hn = hbuf[(t + 1) & 1];
        #pragma unroll
        for (int tl = 0; tl < 2; ++tl) {
            f32x4 p0 = __builtin_amdgcn_mfma_f32_16x16x32_bf16(afr[tl][0], bf0, z4, 0, 0, 0);
            p0 = __builtin_amdgcn_mfma_f32_16x16x32_bf16(afr[tl][1], bf1, p0, 0, 0, 0);
            f32x4 p1 = __builtin_amdgcn_mfma_f32_16x16x32_bf16(afr[tl][2], bf2, z4, 0, 0, 0);
            p1 = __builtin_amdgcn_mfma_f32_16x16x32_bf16(afr[tl][3], bf3, p1, 0, 0, 0);
            const float4 xc = tl ? xc1 : xc0;
            float t0 = tanh_fast(p0[0] + p1[0] + xc.x);
            float t1 = tanh_fast(p0[1] + p1[1] + xc.y);
            float t2 = tanh_fast(p0[2] + p1[2] + xc.z);
            float t3 = tanh_fast(p0[3] + p1[3] + xc.w);
            ushort4 v; v.x = f2bf(t0); v.y = f2bf(t1); v.z = f2bf(t2); v.w = f2bf(t3);
            *(ushort4*)(hn + l16 * LDH + 32 * w + 16 * tl + 4 * quad) = v;
        }
        xc0 = xn0; xc1 = xn1;
        __syncthreads();
    }
    // hT (bf16) in hbuf[0]

    // ---- tail: FC1 -> FC2 -> LN for 16 batches; thread = (n, 8-col group)
    const int n  = tid >> 4;          // batch within block
    const int j0 = (tid & 15) * 8;    // output col group
    const unsigned short* hT = hbuf[0] + n * LDH;

    float s[8];
    #pragma unroll
    for (int i = 0; i < 8; ++i) s[i] = b1[j0 + i];
    for (int k = 0; k < H_DIM; ++k) {
        float hv = bf2f(hT[k]);
        #pragma unroll
        for (int i = 0; i < 8; ++i) s[i] += hv * W1[(j0 + i) * H_DIM + k];
    }
    #pragma unroll
    for (int i = 0; i < 8; ++i) ztmp[n][j0 + i] = fmaxf(s[i], 0.f);
    __syncthreads();

    #pragma unroll
    for (int i = 0; i < 8; ++i) s[i] = b2[j0 + i];
    for (int k = 0; k < H_DIM; ++k) {
        float zv = ztmp[n][k];
        #pragma unroll
        for (int i = 0; i < 8; ++i) s[i] += zv * W2[(j0 + i) * H_DIM + k];
    }
    #pragma unroll
    for (int i = 0; i < 8; ++i) ztmp2[n][j0 + i] = fmaxf(s[i], 0.f);
    __syncthreads();

    // LN: 16 threads per batch, each holds 8 values
    float sum = 0.f, sq = 0.f;
    #pragma unroll
    for (int i = 0; i < 8; ++i) { float v = ztmp2[n][j0 + i]; sum += v; sq += v * v; }
    #pragma unroll
    for (int o = 1; o < 16; o <<= 1) { sum += __shfl_xor(sum, o); sq += __shfl_xor(sq, o); }
    float mu   = sum * (1.f / 128.f);
    float var  = sq * (1.f / 128.f) - mu * mu;
    float rstd = rsqrtf(var + 1e-5f);
    #pragma unroll
    for (int i = 0; i < 8; ++i) {
        int j = j0 + i;
        out[(size_t)(b0 + n) * H_DIM + j] =
            gamma[j] * (ztmp2[n][j] - mu) * rstd + beta[j];
    }
}

// ---------------------------------------------------------------------------
extern "C" void kernel_launch(void* const* d_in, const int* in_sizes, int n_in,
                              void* d_out, int out_size, void* d_ws, size_t ws_size,
                              hipStream_t stream) {
    const float* x     = (const float*)d_in[0];
    const float* W_ih  = (const float*)d_in[1];
    const float* b_ih  = (const float*)d_in[2];
    const float* W_hh  = (const float*)d_in[3];
    const float* b_hh  = (const float*)d_in[4];
    const float* W1    = (const float*)d_in[5];
    const float* b1    = (const float*)d_in[6];
    const float* W2    = (const float*)d_in[7];
    const float* b2    = (const float*)d_in[8];
    const float* gamma = (const float*)d_in[9];
    const float* beta  = (const float*)d_in[10];
    float* out = (float*)d_out;

    float* xp = (float*)d_ws;  // 16 MB

    gemm_xp<<<dim3(M_TOT / BM), dim3(256), 0, stream>>>(x, W_ih, b_ih, b_hh, xp);
    rnn_scan<<<dim3(B_DIM / NB), dim3(256), 0, stream>>>(xp, W_hh, W1, b1, W2, b2,
                                                         gamma, beta, out);
}

// Round 3
// 657.798 us; speedup vs baseline: 1.1036x; 1.1036x over previous
//
#include <hip/hip_runtime.h>

// ---------------------------------------------------------------------------
// xp = x @ W_ih^T + (b_ih + b_hh)   [bf16 MFMA GEMM; lgkm-only barriers,
//                                    2-tile global prefetch ring]
// h_t = tanh(xp_t + W_hh @ h^T)     [MFMA scan; lgkm-only barrier, 4-step
//                                    xp register ring -> loads stay in flight]
// out = LN(relu(relu(hT W1^T+b1) W2^T+b2))   [fused tail]
// ---------------------------------------------------------------------------

typedef __bf16 bf16x8 __attribute__((ext_vector_type(8)));
typedef float  f32x4  __attribute__((ext_vector_type(4)));

#define T_STEPS 512
#define I_DIM   2048
#define H_DIM   128
#define B_DIM   64
#define M_TOT   (B_DIM * T_STEPS)

// LDS-only barrier: does NOT drain vmcnt -> global prefetches stay in flight.
// Safe because all cross-thread data flows through LDS (lgkm) here.
#define LDS_BARRIER() asm volatile("s_waitcnt lgkmcnt(0)\n\ts_barrier" ::: "memory")

__device__ __forceinline__ unsigned short f2bf(float f) {
    unsigned int u = __float_as_uint(f);
    u += 0x7FFFu + ((u >> 16) & 1u);
    return (unsigned short)(u >> 16);
}
__device__ __forceinline__ float bf2f(unsigned short u) {
    return __uint_as_float(((unsigned int)u) << 16);
}
__device__ __forceinline__ bf16x8 packbf8(float4 lo, float4 hi) {
    union { bf16x8 v; unsigned short u[8]; } r;
    r.u[0] = f2bf(lo.x); r.u[1] = f2bf(lo.y); r.u[2] = f2bf(lo.z); r.u[3] = f2bf(lo.w);
    r.u[4] = f2bf(hi.x); r.u[5] = f2bf(hi.y); r.u[6] = f2bf(hi.z); r.u[7] = f2bf(hi.w);
    return r.v;
}
__device__ __forceinline__ float tanh_fast(float a) {
    float q = __expf(a + a);
    return (q - 1.f) * __builtin_amdgcn_rcpf(q + 1.f);
}

// ---------------------------------------------------------------------------
// Kernel 1: xp[M,128] = x[M,2048]bf16 @ W_ih[128,2048]^T bf16 + bias
// BM=64 (grid 512, 2 blk/CU). Register ring depth 2 -> prefetch covers
// ~2 iterations; barriers are lgkm-only so loads survive them.
// ---------------------------------------------------------------------------
#define BM  64
#define BK  64
#define LDK 72
#define NKT (I_DIM / BK)   // 32

__global__ __launch_bounds__(256) void gemm_xp(
    const float* __restrict__ x, const float* __restrict__ w,
    const float* __restrict__ b_ih, const float* __restrict__ b_hh,
    float* __restrict__ xp)
{
    __shared__ __align__(16) unsigned short As[BM * LDK];
    __shared__ __align__(16) unsigned short Bs[H_DIM * LDK];

    const int tid = threadIdx.x;
    const int m0  = blockIdx.x * BM;
    const int r0  = tid >> 4;
    const int c4  = tid & 15;
    const int lane = tid & 63, wave = tid >> 6;
    const int wm = (wave >> 1) * 32;
    const int wn = (wave & 1) * 64;
    const int l16 = lane & 15, quad = lane >> 4;

    f32x4 acc[2][4] = {};
    float4 ar[2][4], br[2][8];

    auto load_tiles = [&](int s, int k0) {
        #pragma unroll
        for (int i = 0; i < 4; ++i)
            ar[s][i] = *(const float4*)(x + (size_t)(m0 + i * 16 + r0) * I_DIM + k0 + c4 * 4);
        #pragma unroll
        for (int i = 0; i < 8; ++i)
            br[s][i] = *(const float4*)(w + (size_t)(i * 16 + r0) * I_DIM + k0 + c4 * 4);
    };
    auto store_tiles = [&](int s) {
        #pragma unroll
        for (int i = 0; i < 4; ++i) {
            ushort4 v; v.x = f2bf(ar[s][i].x); v.y = f2bf(ar[s][i].y);
                       v.z = f2bf(ar[s][i].z); v.w = f2bf(ar[s][i].w);
            *(ushort4*)(As + (i * 16 + r0) * LDK + c4 * 4) = v;
        }
        #pragma unroll
        for (int i = 0; i < 8; ++i) {
            ushort4 v; v.x = f2bf(br[s][i].x); v.y = f2bf(br[s][i].y);
                       v.z = f2bf(br[s][i].z); v.w = f2bf(br[s][i].w);
            *(ushort4*)(Bs + (i * 16 + r0) * LDK + c4 * 4) = v;
        }
    };
    auto mfma_tile = [&]() {
        #pragma unroll
        for (int kt = 0; kt < 2; ++kt) {
            bf16x8 af[2], bfr[4];
            #pragma unroll
            for (int i = 0; i < 2; ++i)
                af[i] = *(const bf16x8*)(As + (wm + i * 16 + l16) * LDK + kt * 32 + quad * 8);
            #pragma unroll
            for (int j = 0; j < 4; ++j)
                bfr[j] = *(const bf16x8*)(Bs + (wn + j * 16 + l16) * LDK + kt * 32 + quad * 8);
            #pragma unroll
            for (int i = 0; i < 2; ++i)
                #pragma unroll
                for (int j = 0; j < 4; ++j)
                    acc[i][j] = __builtin_amdgcn_mfma_f32_16x16x32_bf16(af[i], bfr[j], acc[i][j], 0, 0, 0);
        }
    };

    load_tiles(0, 0);
    load_tiles(1, BK);

    for (int ii = 0; ii < NKT / 2; ++ii) {
        #pragma unroll
        for (int s = 0; s < 2; ++s) {
            const int i  = ii * 2 + s;
            LDS_BARRIER();                 // all frag reads of prev tile done
            store_tiles(s);                // vmcnt wait for ring[s] (2 iters old)
            const int kn = (i + 2) * BK;
            if (kn < I_DIM) load_tiles(s, kn);
            LDS_BARRIER();                 // staged tile visible
            mfma_tile();
        }
    }

    #pragma unroll
    for (int j = 0; j < 4; ++j) {
        const int col = wn + j * 16 + l16;
        const float bias = b_ih[col] + b_hh[col];
        #pragma unroll
        for (int i = 0; i < 2; ++i)
            #pragma unroll
            for (int r = 0; r < 4; ++r) {
                const int row = wm + i * 16 + quad * 4 + r;
                xp[(size_t)(m0 + row) * H_DIM + col] = acc[i][j][r] + bias;
            }
    }
}

// ---------------------------------------------------------------------------
// Kernel 2: MFMA scan. 4 blocks x 256 thr. Per step per wave:
// 4 ds_read_b128 (h B-frags) + 8 MFMA + 8 tanh + 2 ds_write_b64 + 1 barrier.
// xp streamed through a 4-step register ring; barrier never drains vmcnt.
// ---------------------------------------------------------------------------
#define NB  16
#define LDH 136

__global__ __launch_bounds__(256) void rnn_scan(
    const float* __restrict__ xp,
    const float* __restrict__ Whh,
    const float* __restrict__ W1, const float* __restrict__ b1,
    const float* __restrict__ W2, const float* __restrict__ b2,
    const float* __restrict__ gamma, const float* __restrict__ beta,
    float* __restrict__ out)
{
    __shared__ __align__(16) unsigned short hbuf[2][NB * LDH];
    __shared__ float ztmp[NB][129];
    __shared__ float ztmp2[NB][129];

    const int tid  = threadIdx.x;
    const int lane = tid & 63, w = tid >> 6;
    const int l16  = lane & 15, quad = lane >> 4;
    const int b0   = blockIdx.x * NB;

    // W_hh A-frags (static, regs): row = 32w+16t+l16, k = 32ks + 8quad + [0..8)
    bf16x8 afr[2][4];
    #pragma unroll
    for (int t = 0; t < 2; ++t) {
        const float* wrow = Whh + (32 * w + 16 * t + l16) * H_DIM;
        #pragma unroll
        for (int ks = 0; ks < 4; ++ks) {
            float4 lo = *(const float4*)(wrow + 32 * ks + 8 * quad);
            float4 hi = *(const float4*)(wrow + 32 * ks + 8 * quad + 4);
            afr[t][ks] = packbf8(lo, hi);
        }
    }

    // xp: batch = l16, features 32w + 16tl + 4quad + [0..4)
    const float* xpb = xp + (size_t)(b0 + l16) * T_STEPS * H_DIM + 32 * w + 4 * quad;

    // 4-step prefetch ring (~4 x step-time >> 900-cyc HBM latency)
    float4 xr0[4], xr1[4];
    #pragma unroll
    for (int d = 0; d < 4; ++d) {
        xr0[d] = *(const float4*)(xpb + (size_t)d * H_DIM);
        xr1[d] = *(const float4*)(xpb + (size_t)d * H_DIM + 16);
    }

    for (int i = tid; i < NB * LDH; i += 256) hbuf[0][i] = 0;
    __syncthreads();

    const f32x4 z4 = {0.f, 0.f, 0.f, 0.f};
    const int rbase = l16 * LDH + quad * 8;

    for (int t = 0; t < T_STEPS; t += 4) {
        #pragma unroll
        for (int u = 0; u < 4; ++u) {
            const int tt = t + u;
            const unsigned short* hb = hbuf[tt & 1];
            bf16x8 bf0 = *(const bf16x8*)(hb + rbase);
            bf16x8 bf1 = *(const bf16x8*)(hb + rbase + 32);
            bf16x8 bf2 = *(const bf16x8*)(hb + rbase + 64);
            bf16x8 bf3 = *(const bf16x8*)(hb + rbase + 96);

            float4 xc0 = xr0[u], xc1 = xr1[u];
            int tn = tt + 4; if (tn > T_STEPS - 1) tn = T_STEPS - 1;
            xr0[u] = *(const float4*)(xpb + (size_t)tn * H_DIM);
            xr1[u] = *(const float4*)(xpb + (size_t)tn * H_DIM + 16);

            unsigned short* hn = hbuf[(tt + 1) & 1];
            #pragma unroll
            for (int tl = 0; tl < 2; ++tl) {
                f32x4 p0 = __builtin_amdgcn_mfma_f32_16x16x32_bf16(afr[tl][0], bf0, z4, 0, 0, 0);
                p0 = __builtin_amdgcn_mfma_f32_16x16x32_bf16(afr[tl][1], bf1, p0, 0, 0, 0);
                f32x4 p1 = __builtin_amdgcn_mfma_f32_16x16x32_bf16(afr[tl][2], bf2, z4, 0, 0, 0);
                p1 = __builtin_amdgcn_mfma_f32_16x16x32_bf16(afr[tl][3], bf3, p1, 0, 0, 0);
                const float4 xc = tl ? xc1 : xc0;
                float t0 = tanh_fast(p0[0] + p1[0] + xc.x);
                float t1 = tanh_fast(p0[1] + p1[1] + xc.y);
                float t2 = tanh_fast(p0[2] + p1[2] + xc.z);
                float t3 = tanh_fast(p0[3] + p1[3] + xc.w);
                ushort4 v; v.x = f2bf(t0); v.y = f2bf(t1); v.z = f2bf(t2); v.w = f2bf(t3);
                *(ushort4*)(hn + l16 * LDH + 32 * w + 16 * tl + 4 * quad) = v;
            }
            LDS_BARRIER();   // lgkm-only: xp ring loads stay in flight
        }
    }
    // hT (bf16) in hbuf[0]

    const int n  = tid >> 4;
    const int j0 = (tid & 15) * 8;
    const unsigned short* hT = hbuf[0] + n * LDH;

    float s[8];
    #pragma unroll
    for (int i = 0; i < 8; ++i) s[i] = b1[j0 + i];
    for (int k = 0; k < H_DIM; ++k) {
        float hv = bf2f(hT[k]);
        #pragma unroll
        for (int i = 0; i < 8; ++i) s[i] += hv * W1[(j0 + i) * H_DIM + k];
    }
    #pragma unroll
    for (int i = 0; i < 8; ++i) ztmp[n][j0 + i] = fmaxf(s[i], 0.f);
    __syncthreads();

    #pragma unroll
    for (int i = 0; i < 8; ++i) s[i] = b2[j0 + i];
    for (int k = 0; k < H_DIM; ++k) {
        float zv = ztmp[n][k];
        #pragma unroll
        for (int i = 0; i < 8; ++i) s[i] += zv * W2[(j0 + i) * H_DIM + k];
    }
    #pragma unroll
    for (int i = 0; i < 8; ++i) ztmp2[n][j0 + i] = fmaxf(s[i], 0.f);
    __syncthreads();

    float sum = 0.f, sq = 0.f;
    #pragma unroll
    for (int i = 0; i < 8; ++i) { float v = ztmp2[n][j0 + i]; sum += v; sq += v * v; }
    #pragma unroll
    for (int o = 1; o < 16; o <<= 1) { sum += __shfl_xor(sum, o); sq += __shfl_xor(sq, o); }
    float mu   = sum * (1.f / 128.f);
    float var  = sq * (1.f / 128.f) - mu * mu;
    float rstd = rsqrtf(var + 1e-5f);
    #pragma unroll
    for (int i = 0; i < 8; ++i) {
        int j = j0 + i;
        out[(size_t)(b0 + n) * H_DIM + j] =
            gamma[j] * (ztmp2[n][j] - mu) * rstd + beta[j];
    }
}

// ---------------------------------------------------------------------------
extern "C" void kernel_launch(void* const* d_in, const int* in_sizes, int n_in,
                              void* d_out, int out_size, void* d_ws, size_t ws_size,
                              hipStream_t stream) {
    const float* x     = (const float*)d_in[0];
    const float* W_ih  = (const float*)d_in[1];
    const float* b_ih  = (const float*)d_in[2];
    const float* W_hh  = (const float*)d_in[3];
    const float* b_hh  = (const float*)d_in[4];
    const float* W1    = (const float*)d_in[5];
    const float* b1    = (const float*)d_in[6];
    const float* W2    = (const float*)d_in[7];
    const float* b2    = (const float*)d_in[8];
    const float* gamma = (const float*)d_in[9];
    const float* beta  = (const float*)d_in[10];
    float* out = (float*)d_out;

    float* xp = (float*)d_ws;

    gemm_xp<<<dim3(M_TOT / BM), dim3(256), 0, stream>>>(x, W_ih, b_ih, b_hh, xp);
    rnn_scan<<<dim3(B_DIM / NB), dim3(256), 0, stream>>>(xp, W_hh, W1, b1, W2, b2,
                                                         gamma, beta, out);
}